// Round 3
// baseline (90.807 us; speedup 1.0000x reference)
//
#include <hip/hip_runtime.h>
#include <math.h>

// Level geometry (fixed by reference: strides 4/8/16, H=W=160/80/40)
#define NL0 25600   // 160*160
#define NL1 6400    // 80*80
#define NL2 1600    // 40*40
#define MAXM 64
#define ANCH 2      // anchors per thread (pair along x, same row) -- R1-proven best
#define TPB 256
#define APB (TPB * ANCH)   // 512 anchors per block
// Level-pure blocks: per-block box cull uses a single (low, high, y-range).
#define GX0 50      // 25600 / 512
#define GX1 13      // ceil(6400 / 512)
#define GX2 4       // ceil(1600 / 512)
#define GX  (GX0 + GX1 + GX2)   // 67
#define NB 16
#define NPART (GX * NB)         // 1072 partial slots

// ws layout (bytes):
//   [0, 12864)        part: 3*NPART floats (cls | reg | pos)
//   [12928, 15104)    counters: cnt[16] (one per 128B line) + gcnt (17 lines)
//   [15104, 15296)    image sums: isC[16] | isR[16] | isP[16]
// Counters are memset to 0 each launch (ws is re-poisoned by the harness).
#define CNT_OFF  12928
#define CNT_LINES 17
#define ISUM_OFF (CNT_OFF + CNT_LINES * 128)

// Fused kernel: main work + two-level last-block-arrives reduction.
// No kernel waits on anything (the last arriver does the work) -> no
// co-residency assumption, no deadlock risk. Cross-XCD visibility via
// agent-scope release(fetch_add)/acquire chain (Guideline 16).
__global__ __launch_bounds__(TPB, 1) void fcos_fused(
    const float* __restrict__ cls0, const float* __restrict__ cls1,
    const float* __restrict__ cls2, const float* __restrict__ reg0,
    const float* __restrict__ reg1, const float* __restrict__ reg2,
    const float* __restrict__ boxes, int M, int B,
    float* part, unsigned* cnts, float* isum, float* out)
{
    const int b  = blockIdx.y;
    const int lx = blockIdx.x;

    // --- block-uniform level resolve (wave-uniform branch) ---
    int ii0, W, hw; float s, low, high;
    const float* cb; const float* rb;
    if (lx < GX0) {
        ii0 = lx * APB;               W = 160; hw = NL0; s = 4.0f;
        low = -1.0f;  high = 64.0f;   cb = cls0; rb = reg0;
    } else if (lx < GX0 + GX1) {
        ii0 = (lx - GX0) * APB;       W = 80;  hw = NL1; s = 8.0f;
        low = 64.0f;  high = 128.0f;  cb = cls1; rb = reg1;
    } else {
        ii0 = (lx - GX0 - GX1) * APB; W = 40;  hw = NL2; s = 16.0f;
        low = 128.0f; high = 99999.0f; cb = cls2; rb = reg2;
    }

    const int r0 = ii0 / W;
    const int r1 = min(ii0 + APB - 1, hw - 1) / W;
    const float ymin = ((float)r0 + 0.5f) * s;
    const float ymax = ((float)r1 + 0.5f) * s;

    __shared__ float4   sbox[MAXM];    // full table (epilogue gather by ORIGINAL j)
    __shared__ float4   cbox[MAXM];    // culled+compacted boxes for the hot loop
    __shared__ unsigned cpk[MAXM];     // compacted packed argmin keys (original j kept)
    __shared__ int      scnt;

    // --- wave-0 cull + compact (conservative-exact, see R1) ---
    if (threadIdx.x < 64) {
        const int j = threadIdx.x;
        float4 bx = make_float4(0.f, 0.f, 0.f, 0.f);
        unsigned pk = 0xFFFFFFFFu;
        bool keep = false;
        if (j < M) {
            bx = ((const float4*)boxes)[(size_t)b * M + j];
            const float bw = bx.z - bx.x, bh = bx.w - bx.y;
            const float area = bw * bh;
            pk = (__float_as_uint(area) & ~63u) | (unsigned)j;
            const float dmax = fmaxf(bw, bh);
            keep = (dmax > low) & (dmax < 2.0f * high) & (bx.y < ymax) & (bx.w > ymin);
        }
        sbox[j] = bx;
        const unsigned long long mk = __ballot(keep);
        if (keep) {
            const int pos = (int)__popcll(mk & ((1ull << j) - 1ull));
            cbox[pos] = bx;
            cpk[pos]  = pk;
        }
        if (j == 0) scnt = (int)__popcll(mk);
    }
    __syncthreads();
    const int cnt = scnt;

    float clsl = 0.0f, regl = 0.0f, posf = 0.0f;

    const int ii = ii0 + (int)threadIdx.x * ANCH;
    if (ii < hw) {
        const int h = ii / W, w = ii - h * W;   // pair never crosses a row (W even)
        const float x0 = ((float)w + 0.5f) * s;
        const float y  = ((float)h + 0.5f) * s;
        const float xk[ANCH] = { x0, x0 + s };

        // Hoist epilogue global loads so their latency overlaps the M-loop.
        const float* rp = rb + (size_t)b * 4 * hw + ii;
        const float2 pl2 = *(const float2*)(rp);
        const float2 pt2 = *(const float2*)(rp + hw);
        const float2 pr2 = *(const float2*)(rp + 2 * hw);
        const float2 pb2 = *(const float2*)(rp + 3 * hw);
        const float2 lg2 = *(const float2*)(cb + (size_t)b * hw + ii);
        const float plv[2] = { pl2.x, pl2.y };
        const float ptv[2] = { pt2.x, pt2.y };
        const float prv[2] = { pr2.x, pr2.y };
        const float pbv[2] = { pb2.x, pb2.y };
        const float lgv[2] = { lg2.x, lg2.y };

        unsigned best[ANCH] = { 0xFFFFFFFFu, 0xFFFFFFFFu };

        #pragma unroll 2
        for (int j = 0; j < cnt; ++j) {
            const float4 bx = cbox[j];          // broadcast ds_read_b128
            const unsigned pk = cpk[j];
            const float t   = y - bx.y;
            const float bo  = bx.w - y;
            const float mtb = fminf(t, bo);
            const float xtb = fmaxf(t, bo);
            const float l0  = x0 - bx.x;
            const float r0f = bx.z - x0;
            #pragma unroll
            for (int k = 0; k < ANCH; ++k) {
                const float ks = (float)k * s;
                const float l = l0 + ks;
                const float r = r0f - ks;
                const float mn = fminf(fminf(l, r), mtb);   // v_min3
                const float mx = fmaxf(fmaxf(l, r), xtb);   // v_max3
                const bool ok = (mn > 0.0f) & (mx > low) & (mx < high);
                const unsigned cand = ok ? pk : 0xFFFFFFFFu;
                best[k] = min(best[k], cand);
            }
        }

        #pragma unroll
        for (int k = 0; k < ANCH; ++k) {
            const bool pos = (best[k] != 0xFFFFFFFFu);
            const int idx = (int)(best[k] & 63u);
            const float4 tbx = sbox[idx];       // divergent gather, 1/anchor
            const float xc = xk[k];
            const float tl = xc - tbx.x, tt = y - tbx.y;
            const float tr = tbx.z - xc, tb = tbx.w - y;

            const float pl = plv[k], pt = ptv[k], pr = prv[k], pb = pbv[k];

            const float w_i = fminf(pl, tl) + fminf(pr, tr);
            const float h_i = fminf(pt, tt) + fminf(pb, tb);
            const float a_i = fmaxf(w_i, 0.0f) * fmaxf(h_i, 0.0f);
            const float a_p = (pl + pr) * (pt + pb);
            const float a_t = (tl + tr) * (tt + tb);
            const float a_u = a_p + a_t - a_i + 1e-7f;
            const float iou_raw = a_i / a_u;

            const float w_e = fmaxf(pl, tl) + fmaxf(pr, tr);
            const float h_e = fmaxf(pt, tt) + fmaxf(pb, tb);
            const float a_e = fmaxf(w_e, 0.0f) * fmaxf(h_e, 0.0f) + 1e-7f;
            const float gl = 1.0f - (iou_raw - (a_e - a_u) / a_e);

            regl += pos ? gl : 0.0f;
            posf += pos ? 1.0f : 0.0f;
            const float gt_iou = pos ? fminf(fmaxf(iou_raw, 0.0f), 1.0f) : 0.0f;

            // Shared logsig pieces: bit-identical to logsig(x), logsig(-x)
            const float logit = lgv[k];
            const float e   = expf(-fabsf(logit));
            const float l1p = log1pf(e);
            const float log_p  = fminf(logit, 0.0f) - l1p;
            const float log_np = fminf(-logit, 0.0f) - l1p;
            const float p = 1.0f / (1.0f + expf(-logit));
            if (gt_iou > 0.0f)
                clsl += -gt_iou * (gt_iou * log_p + (1.0f - gt_iou) * log_np);
            else
                clsl += -0.75f * p * p * log_np;
        }
    }

    // ---- block reduction: wave shuffle then cross-wave via LDS ----
    __shared__ float red[3][TPB / 64];
    __shared__ int sflag;
    const int lane = threadIdx.x & 63;
    const int wv   = threadIdx.x >> 6;

    float v0 = clsl, v1 = regl, v2 = posf;
    #pragma unroll
    for (int off = 32; off > 0; off >>= 1) {
        v0 += __shfl_down(v0, off);
        v1 += __shfl_down(v1, off);
        v2 += __shfl_down(v2, off);
    }
    if (lane == 0) { red[0][wv] = v0; red[1][wv] = v1; red[2][wv] = v2; }
    __syncthreads();
    if (threadIdx.x == 0) {
        float s0 = 0, s1 = 0, s2 = 0;
        #pragma unroll
        for (int wvi = 0; wvi < TPB / 64; ++wvi) { s0 += red[0][wvi]; s1 += red[1][wvi]; s2 += red[2][wvi]; }
        const int p = b * GX + lx;
        __hip_atomic_store(&part[p],             s0, __ATOMIC_RELAXED, __HIP_MEMORY_SCOPE_AGENT);
        __hip_atomic_store(&part[NPART + p],     s1, __ATOMIC_RELAXED, __HIP_MEMORY_SCOPE_AGENT);
        __hip_atomic_store(&part[2 * NPART + p], s2, __ATOMIC_RELAXED, __HIP_MEMORY_SCOPE_AGENT);
        // per-image counter: own 128B line -> only GX=67 RMWs per line, overlapped
        const unsigned r = __hip_atomic_fetch_add(&cnts[b * 32], 1u,
                                                  __ATOMIC_ACQ_REL, __HIP_MEMORY_SCOPE_AGENT);
        sflag = (r == GX - 1);
    }
    __syncthreads();

    if (sflag) {
        // ---- stage 1: last block of image b reduces its 67 partials ----
        float u0 = 0, u1 = 0, u2 = 0;
        if (threadIdx.x < GX) {
            const int q = b * GX + threadIdx.x;
            u0 = __hip_atomic_load(&part[q],             __ATOMIC_RELAXED, __HIP_MEMORY_SCOPE_AGENT);
            u1 = __hip_atomic_load(&part[NPART + q],     __ATOMIC_RELAXED, __HIP_MEMORY_SCOPE_AGENT);
            u2 = __hip_atomic_load(&part[2 * NPART + q], __ATOMIC_RELAXED, __HIP_MEMORY_SCOPE_AGENT);
        }
        #pragma unroll
        for (int off = 32; off > 0; off >>= 1) {
            u0 += __shfl_down(u0, off);
            u1 += __shfl_down(u1, off);
            u2 += __shfl_down(u2, off);
        }
        if (lane == 0) { red[0][wv] = u0; red[1][wv] = u1; red[2][wv] = u2; }
        __syncthreads();
        if (threadIdx.x == 0) {
            float t0 = 0, t1 = 0, t2 = 0;
            #pragma unroll
            for (int wvi = 0; wvi < TPB / 64; ++wvi) { t0 += red[0][wvi]; t1 += red[1][wvi]; t2 += red[2][wvi]; }
            __hip_atomic_store(&isum[b],      t0, __ATOMIC_RELAXED, __HIP_MEMORY_SCOPE_AGENT);
            __hip_atomic_store(&isum[16 + b], t1, __ATOMIC_RELAXED, __HIP_MEMORY_SCOPE_AGENT);
            __hip_atomic_store(&isum[32 + b], t2, __ATOMIC_RELAXED, __HIP_MEMORY_SCOPE_AGENT);
            const unsigned g = __hip_atomic_fetch_add(&cnts[16 * 32], 1u,
                                                      __ATOMIC_ACQ_REL, __HIP_MEMORY_SCOPE_AGENT);
            sflag = (g == (unsigned)B - 1);
        }
        __syncthreads();

        if (sflag) {
            // ---- stage 2: global-last block reduces B image sums, writes out ----
            if (threadIdx.x < 64) {
                float f0 = 0, f1 = 0, f2 = 0;
                if (threadIdx.x < B) {
                    f0 = __hip_atomic_load(&isum[threadIdx.x],      __ATOMIC_RELAXED, __HIP_MEMORY_SCOPE_AGENT);
                    f1 = __hip_atomic_load(&isum[16 + threadIdx.x], __ATOMIC_RELAXED, __HIP_MEMORY_SCOPE_AGENT);
                    f2 = __hip_atomic_load(&isum[32 + threadIdx.x], __ATOMIC_RELAXED, __HIP_MEMORY_SCOPE_AGENT);
                }
                #pragma unroll
                for (int off = 32; off > 0; off >>= 1) {
                    f0 += __shfl_down(f0, off);
                    f1 += __shfl_down(f1, off);
                    f2 += __shfl_down(f2, off);
                }
                if (threadIdx.x == 0) {
                    const float navg = fmaxf(1.0f, f2 / (float)B);
                    out[0] = (f0 + f1) / navg;
                    out[1] = f0 / navg;
                    out[2] = f1 / navg;
                }
            }
        }
    }
}

extern "C" void kernel_launch(void* const* d_in, const int* in_sizes, int n_in,
                              void* d_out, int out_size, void* d_ws, size_t ws_size,
                              hipStream_t stream) {
    const float* cls0 = (const float*)d_in[0];
    const float* cls1 = (const float*)d_in[1];
    const float* cls2 = (const float*)d_in[2];
    const float* reg0 = (const float*)d_in[3];
    const float* reg1 = (const float*)d_in[4];
    const float* reg2 = (const float*)d_in[5];
    const float* boxes = (const float*)d_in[6];

    const int B = in_sizes[0] / NL0;          // 16
    const int M = in_sizes[6] / (4 * B);      // 64 (<= MAXM)

    float*    part = (float*)d_ws;
    unsigned* cnts = (unsigned*)((char*)d_ws + CNT_OFF);
    float*    isum = (float*)((char*)d_ws + ISUM_OFF);

    // zero the 17 counter lines (ws is re-poisoned by the harness each iter)
    hipMemsetAsync(cnts, 0, CNT_LINES * 128, stream);

    dim3 grid(GX, B);
    fcos_fused<<<grid, TPB, 0, stream>>>(cls0, cls1, cls2, reg0, reg1, reg2,
                                         boxes, M, B, part, cnts, isum,
                                         (float*)d_out);
}

// Round 4
// 78.499 us; speedup vs baseline: 1.1568x; 1.1568x over previous
//
#include <hip/hip_runtime.h>
#include <math.h>

// Level geometry (fixed by reference: strides 4/8/16, H=W=160/80/40)
#define NL0 25600   // 160*160
#define NL1 6400    // 80*80
#define NL2 1600    // 40*40
#define MAXM 64
#define ANCH 2      // anchors per thread (pair along x, same row)
#define TPB 256
#define APB (TPB * ANCH)   // 512 anchors per block
// Level-pure blocks: no block straddles a level boundary, so the per-block
// box cull can use a single (low, high, y-range).
#define GX0 50      // 25600 / 512
#define GX1 13      // ceil(6400 / 512)  (last block half-active)
#define GX2 4       // ceil(1600 / 512)  (last block 1/8-active)
#define GX  (GX0 + GX1 + GX2)   // 67
#define NB 16
#define NPART (GX * NB)         // 1072 partial slots

// ws layout (floats): cls_part[NPART] | reg_part[NPART] | pos_part[NPART]
// NO global atomics anywhere (R6 win: serialized same-line atomic RMWs).
// R3 lesson: last-block-arrives fusion REGRESSES (+11.6us) -- the ACQ_REL
// cross-XCD acquire chain lands on the grid critical path; keep 2 kernels.
__global__ __launch_bounds__(TPB, 1) void fcos_main(
    const float* __restrict__ cls0, const float* __restrict__ cls1,
    const float* __restrict__ cls2, const float* __restrict__ reg0,
    const float* __restrict__ reg1, const float* __restrict__ reg2,
    const float* __restrict__ boxes, int M, float* __restrict__ part)
{
    const int b  = blockIdx.y;
    const int lx = blockIdx.x;

    // --- block-uniform level resolve (wave-uniform branch) ---
    int ii0, W, hw; float s, low, high;
    const float* cb; const float* rb;
    if (lx < GX0) {
        ii0 = lx * APB;               W = 160; hw = NL0; s = 4.0f;
        low = -1.0f;  high = 64.0f;   cb = cls0; rb = reg0;
    } else if (lx < GX0 + GX1) {
        ii0 = (lx - GX0) * APB;       W = 80;  hw = NL1; s = 8.0f;
        low = 64.0f;  high = 128.0f;  cb = cls1; rb = reg1;
    } else {
        ii0 = (lx - GX0 - GX1) * APB; W = 40;  hw = NL2; s = 16.0f;
        low = 128.0f; high = 99999.0f; cb = cls2; rb = reg2;
    }

    // Block anchor-y range (exact fp32: (row+0.5)*s is exact for these values)
    const int r0 = ii0 / W;
    const int r1 = min(ii0 + APB - 1, hw - 1) / W;
    const float ymin = ((float)r0 + 0.5f) * s;
    const float ymax = ((float)r1 + 0.5f) * s;

    __shared__ float4   sbox[MAXM];    // full table, indexed by ORIGINAL j (epilogue gather)
    __shared__ float4   cbox[MAXM];    // culled+compacted boxes for the hot loop
    __shared__ unsigned cpk[MAXM];     // compacted packed argmin keys (keep original j!)
    __shared__ int      scnt;

    // --- wave-0 cull + compact ---
    // Eligibility needs in_box AND in_lvl. Conservative-exact rejects:
    //  (a) y1 <= ymin or y0 >= ymax  -> no anchor in block strictly inside box
    //  (b) max(bw,bh) <= low         -> mx < max(bw,bh) <= low, in_lvl fails
    //  (c) max(bw,bh) >= 2*high      -> mx >= max(bw,bh)/2 >= high, in_lvl fails
    // (b) kills ALL boxes at L2 for this data; (a) keeps ~11% at L0.
    if (threadIdx.x < 64) {
        const int j = threadIdx.x;
        float4 bx = make_float4(0.f, 0.f, 0.f, 0.f);
        unsigned pk = 0xFFFFFFFFu;
        bool keep = false;
        if (j < M) {
            bx = ((const float4*)boxes)[(size_t)b * M + j];
            const float bw = bx.z - bx.x, bh = bx.w - bx.y;
            const float area = bw * bh;
            // (area_bits & ~63) | j : argmin with first-index tie-break (verified scheme)
            pk = (__float_as_uint(area) & ~63u) | (unsigned)j;
            const float dmax = fmaxf(bw, bh);
            keep = (dmax > low) & (dmax < 2.0f * high) & (bx.y < ymax) & (bx.w > ymin);
        }
        sbox[j] = bx;
        const unsigned long long mk = __ballot(keep);
        if (keep) {
            const int pos = (int)__popcll(mk & ((1ull << j) - 1ull));
            cbox[pos] = bx;
            cpk[pos]  = pk;
        }
        if (j == 0) scnt = (int)__popcll(mk);
    }
    __syncthreads();
    const int cnt = scnt;

    float clsl = 0.0f, regl = 0.0f, posf = 0.0f;

    const int ii = ii0 + (int)threadIdx.x * ANCH;   // level-relative anchor index
    if (ii < hw) {
        const int h = ii / W, w = ii - h * W;       // ANCH=2 pair never crosses a row (W even)
        const float x0 = ((float)w + 0.5f) * s;
        const float y  = ((float)h + 0.5f) * s;
        const float xk[ANCH] = { x0, x0 + s };

        // Hoist epilogue global loads so their latency overlaps the M-loop.
        const float* rp = rb + (size_t)b * 4 * hw + ii;
        const float2 pl2 = *(const float2*)(rp);
        const float2 pt2 = *(const float2*)(rp + hw);
        const float2 pr2 = *(const float2*)(rp + 2 * hw);
        const float2 pb2 = *(const float2*)(rp + 3 * hw);
        const float2 lg2 = *(const float2*)(cb + (size_t)b * hw + ii);
        const float plv[2] = { pl2.x, pl2.y };
        const float ptv[2] = { pt2.x, pt2.y };
        const float prv[2] = { pr2.x, pr2.y };
        const float pbv[2] = { pb2.x, pb2.y };
        const float lgv[2] = { lg2.x, lg2.y };

        unsigned best[ANCH] = { 0xFFFFFFFFu, 0xFFFFFFFFu };

        #pragma unroll 2
        for (int j = 0; j < cnt; ++j) {
            const float4 bx = cbox[j];          // broadcast ds_read_b128
            const unsigned pk = cpk[j];
            const float t   = y - bx.y;
            const float bo  = bx.w - y;
            const float mtb = fminf(t, bo);
            const float xtb = fmaxf(t, bo);
            const float l0  = x0 - bx.x;
            const float r0f = bx.z - x0;
            #pragma unroll
            for (int k = 0; k < ANCH; ++k) {
                const float ks = (float)k * s;
                const float l = l0 + ks;
                const float r = r0f - ks;
                const float mn = fminf(fminf(l, r), mtb);   // v_min3
                const float mx = fmaxf(fmaxf(l, r), xtb);   // v_max3
                const bool ok = (mn > 0.0f) & (mx > low) & (mx < high);
                const unsigned cand = ok ? pk : 0xFFFFFFFFu;
                best[k] = min(best[k], cand);
            }
        }

        #pragma unroll
        for (int k = 0; k < ANCH; ++k) {
            const bool pos = (best[k] != 0xFFFFFFFFu);
            const int idx = (int)(best[k] & 63u);
            const float4 tbx = sbox[idx];       // divergent gather, 1/anchor
            const float xc = xk[k];
            const float tl = xc - tbx.x, tt = y - tbx.y;
            const float tr = tbx.z - xc, tb = tbx.w - y;

            const float pl = plv[k], pt = ptv[k], pr = prv[k], pb = pbv[k];

            const float w_i = fminf(pl, tl) + fminf(pr, tr);
            const float h_i = fminf(pt, tt) + fminf(pb, tb);
            const float a_i = fmaxf(w_i, 0.0f) * fmaxf(h_i, 0.0f);
            const float a_p = (pl + pr) * (pt + pb);
            const float a_t = (tl + tr) * (tt + tb);
            const float a_u = a_p + a_t - a_i + 1e-7f;
            const float iou_raw = a_i / a_u;

            const float w_e = fmaxf(pl, tl) + fmaxf(pr, tr);
            const float h_e = fmaxf(pt, tt) + fmaxf(pb, tb);
            const float a_e = fmaxf(w_e, 0.0f) * fmaxf(h_e, 0.0f) + 1e-7f;
            const float gl = 1.0f - (iou_raw - (a_e - a_u) / a_e);

            regl += pos ? gl : 0.0f;
            posf += pos ? 1.0f : 0.0f;
            const float gt_iou = pos ? fminf(fmaxf(iou_raw, 0.0f), 1.0f) : 0.0f;

            // Shared logsig pieces: bit-identical to logsig(x), logsig(-x)
            const float logit = lgv[k];
            const float e   = expf(-fabsf(logit));
            const float l1p = log1pf(e);
            const float log_p  = fminf(logit, 0.0f) - l1p;
            const float log_np = fminf(-logit, 0.0f) - l1p;
            const float p = 1.0f / (1.0f + expf(-logit));
            if (gt_iou > 0.0f)
                clsl += -gt_iou * (gt_iou * log_p + (1.0f - gt_iou) * log_np);
            else
                clsl += -0.75f * p * p * log_np;
        }
    }

    // block reduction: wave shuffle (width 64) then cross-wave via LDS
    float v0 = clsl, v1 = regl, v2 = posf;
    #pragma unroll
    for (int off = 32; off > 0; off >>= 1) {
        v0 += __shfl_down(v0, off);
        v1 += __shfl_down(v1, off);
        v2 += __shfl_down(v2, off);
    }
    __shared__ float red[3][TPB / 64];
    const int lane = threadIdx.x & 63;
    const int wv   = threadIdx.x >> 6;
    if (lane == 0) { red[0][wv] = v0; red[1][wv] = v1; red[2][wv] = v2; }
    __syncthreads();
    if (threadIdx.x == 0) {
        float s0 = 0, s1 = 0, s2 = 0;
        #pragma unroll
        for (int wvi = 0; wvi < TPB / 64; ++wvi) { s0 += red[0][wvi]; s1 += red[1][wvi]; s2 += red[2][wvi]; }
        const int p = blockIdx.y * GX + blockIdx.x;
        part[p]             = s0;
        part[NPART + p]     = s1;
        part[2 * NPART + p] = s2;
    }
}

__global__ __launch_bounds__(TPB) void fcos_final(
    const float* __restrict__ part, float* __restrict__ out, int B)
{
    float s0 = 0.0f, s1 = 0.0f, s2 = 0.0f;
    for (int i = threadIdx.x; i < NPART; i += TPB) {
        s0 += part[i];
        s1 += part[NPART + i];
        s2 += part[2 * NPART + i];
    }
    #pragma unroll
    for (int off = 32; off > 0; off >>= 1) {
        s0 += __shfl_down(s0, off);
        s1 += __shfl_down(s1, off);
        s2 += __shfl_down(s2, off);
    }
    __shared__ float red[3][TPB / 64];
    const int lane = threadIdx.x & 63;
    const int wv   = threadIdx.x >> 6;
    if (lane == 0) { red[0][wv] = s0; red[1][wv] = s1; red[2][wv] = s2; }
    __syncthreads();
    if (threadIdx.x == 0) {
        float cls_sum = 0, reg_sum = 0, npos = 0;
        #pragma unroll
        for (int wvi = 0; wvi < TPB / 64; ++wvi) {
            cls_sum += red[0][wvi]; reg_sum += red[1][wvi]; npos += red[2][wvi];
        }
        const float navg = fmaxf(1.0f, npos / (float)B);
        out[0] = (cls_sum + reg_sum) / navg;
        out[1] = cls_sum / navg;
        out[2] = reg_sum / navg;
    }
}

extern "C" void kernel_launch(void* const* d_in, const int* in_sizes, int n_in,
                              void* d_out, int out_size, void* d_ws, size_t ws_size,
                              hipStream_t stream) {
    const float* cls0 = (const float*)d_in[0];
    const float* cls1 = (const float*)d_in[1];
    const float* cls2 = (const float*)d_in[2];
    const float* reg0 = (const float*)d_in[3];
    const float* reg1 = (const float*)d_in[4];
    const float* reg2 = (const float*)d_in[5];
    const float* boxes = (const float*)d_in[6];

    const int B = in_sizes[0] / NL0;          // 16
    const int M = in_sizes[6] / (4 * B);      // 64 (<= MAXM)

    float* part = (float*)d_ws;               // 3 * NPART floats = 12.9 KB

    dim3 grid(GX, B);
    fcos_main<<<grid, TPB, 0, stream>>>(cls0, cls1, cls2, reg0, reg1, reg2,
                                        boxes, M, part);
    fcos_final<<<1, TPB, 0, stream>>>(part, (float*)d_out, B);
}